// Round 8
// baseline (362.307 us; speedup 1.0000x reference)
//
#include <hip/hip_runtime.h>
#include <hip/hip_bf16.h>
#include <cstdint>

// MHA fwd: B=4, L=2048, HIDDEN=1024, HEADS=16, HEAD_DIM=64. fp32 in/out,
// bf16 MFMA internally (fp32 accum everywhere).
#define HIDDEN 1024
#define HEADS 16
#define HEAD_DIM 64
#define BATCH 4
#define SEQ 2048
#define TOK (BATCH * SEQ) /* 8192 */

typedef __attribute__((ext_vector_type(8))) short short8;   // 8 bf16 (4 VGPRs)
typedef __attribute__((ext_vector_type(4))) float f32x4;
typedef __attribute__((ext_vector_type(16))) float f32x16;

__device__ __forceinline__ void gload_lds16(const void* g, void* s) {
  // global -> LDS direct, 16B/lane; LDS dest = wave-uniform base + lane*16
  __builtin_amdgcn_global_load_lds(
      (const __attribute__((address_space(1))) void*)g,
      (__attribute__((address_space(3))) void*)s, 16, 0, 0);
}

__device__ __forceinline__ unsigned short f2bf(float x) {
  union { __hip_bfloat16 h; unsigned short u; } c;
  c.h = __float2bfloat16(x);
  return c.u;
}

// HW packed f32->bf16 (RNE), lo = first arg (T12 recipe; no builtin on gfx950)
__device__ __forceinline__ uint32_t cvt_pk_bf16(float lo, float hi) {
  uint32_t r;
  asm("v_cvt_pk_bf16_f32 %0, %1, %2" : "=v"(r) : "v"(lo), "v"(hi));
  return r;
}

__device__ __forceinline__ f32x4 mfma16(short8 a, short8 b, f32x4 c) {
  return __builtin_amdgcn_mfma_f32_16x16x32_bf16(a, b, c, 0, 0, 0);
}

// ---------------------------------------------------------------- conversions
__global__ __launch_bounds__(256) void convert_f32_bf16(
    const float* __restrict__ in, __hip_bfloat16* __restrict__ out, int n4) {
  int idx = blockIdx.x * blockDim.x + threadIdx.x;
  int stride = gridDim.x * blockDim.x;
  for (int i = idx; i < n4; i += stride) {
    float4 v = ((const float4*)in)[i];
    union { ushort4 u; __hip_bfloat16 h[4]; } r;
    r.h[0] = __float2bfloat16(v.x);
    r.h[1] = __float2bfloat16(v.y);
    r.h[2] = __float2bfloat16(v.z);
    r.h[3] = __float2bfloat16(v.w);
    ((ushort4*)out)[i] = r.u;
  }
}

// W [K=1024][N=1024] fp32 -> Wt [N][K] bf16 (64x64 LDS tile transpose)
__global__ __launch_bounds__(256) void transpose_to_bf16(
    const float* __restrict__ in, __hip_bfloat16* __restrict__ out) {
  __shared__ __hip_bfloat16 t[64][65];
  const int tx = threadIdx.x & 63;
  const int ty = threadIdx.x >> 6; // 0..3
  const int k0 = blockIdx.y * 64;
  const int n0 = blockIdx.x * 64;
#pragma unroll
  for (int i = 0; i < 16; ++i) {
    int r = i * 4 + ty;
    t[r][tx] = __float2bfloat16(in[(size_t)(k0 + r) * 1024 + n0 + tx]);
  }
  __syncthreads();
#pragma unroll
  for (int i = 0; i < 16; ++i) {
    int r = i * 4 + ty;
    out[(size_t)(n0 + r) * 1024 + k0 + tx] = t[tx][r];
  }
}

// ------------------------------------------------------- GEMM 256^2, 8-phase
// C[M=8192, N=3072] = A[M,1024] @ Bt[N,1024]^T, fused QKV bias+scatter epi.
// 512 thr = 8 waves (2M x 4N); per-wave C = 128x64; BK=64, 16 K-tiles.
// LDS 128KB: [dbuf=2][region: A-h0,A-h1,B-h0,B-h1][16KB = 128 rows x 128B].
// st_16x32 swizzle (T2): LDS[row][c] holds G[row][c ^ ((row&4)<<3)]; dest of
// global_load_lds stays LINEAR, source col pre-swizzled, ds_read applies the
// same XOR (rule 21 both-sides).
// Schedule (T3/T4): per K-tile 4 phases {ds_read quad frags; barrier; setprio;
// 16 MFMA; setprio; barrier}; at ph3 stage K-tile kt+2 into buf[cur] (safe:
// all reads of buf[cur] completed by ph2's trailing barrier), then vmcnt(8)
// retires kt+1's 8 stage-instructions, barrier publishes. Never vmcnt(0) in
// steady state. Raw s_barrier (NOT __syncthreads — that drains vmcnt).
__global__ __launch_bounds__(512, 2) void gemm256_qkv(
    const __hip_bfloat16* __restrict__ A, const __hip_bfloat16* __restrict__ Bt,
    const float* __restrict__ bq, const float* __restrict__ bk,
    const float* __restrict__ bv, __hip_bfloat16* __restrict__ Qb,
    __hip_bfloat16* __restrict__ Kb, __hip_bfloat16* __restrict__ VTb) {
  __shared__ __align__(16) char lds[2][4][16384];
  const int tid = threadIdx.x;
  const int wv = tid >> 6, l = tid & 63;
  const int lc = l & 15, lg4 = l >> 4;

  // XCD-bijective block swizzle (T1; grid 384 % 8 == 0)
  const int nwg = gridDim.x, cpx = nwg >> 3;
  const int bid = (blockIdx.x & 7) * cpx + (blockIdx.x >> 3);
  const int tm = bid / 12, tn = bid % 12; // N/256 = 12
  const int bm0 = tm * 256, bn0 = tn * 256;

  const int wm = wv >> 2, wn = wv & 3;

  // staging lane geometry: call covers 64 rows; wave wv rows 8wv..8wv+7
  const int r0 = 8 * wv + (l >> 3);
  const int scol = (16 * (l & 7)) ^ ((l & 32) ? 32 : 0); // pre-swizzled G col
  const char* Ab = (const char*)A;
  const char* Bb = (const char*)Bt;

#define ST1(buf, reg, gB, rowb, kt, c)                                        \
  gload_lds16(gB + (size_t)((rowb) + 64 * (c) + r0) * 2048 +                  \
                  (size_t)(kt) * 128 + scol,                                  \
              &lds[buf][reg][(c) * 8192 + wv * 1024])
#define STAGE_KT(buf, kt)                                                     \
  {                                                                           \
    ST1(buf, 0, Ab, bm0, kt, 0);                                              \
    ST1(buf, 0, Ab, bm0, kt, 1);                                              \
    ST1(buf, 1, Ab, bm0 + 128, kt, 0);                                        \
    ST1(buf, 1, Ab, bm0 + 128, kt, 1);                                        \
    ST1(buf, 2, Bb, bn0, kt, 0);                                              \
    ST1(buf, 2, Bb, bn0, kt, 1);                                              \
    ST1(buf, 3, Bb, bn0 + 128, kt, 0);                                        \
    ST1(buf, 3, Bb, bn0 + 128, kt, 1);                                        \
  }

  // frag-read lane constants: byte = row_l*128 + 64*ks + alg,
  // alg folds 16*lg4 with the (lc&4) swizzle bit
  const int alg = (16 * lg4) ^ ((lc & 4) << 3);
  const int brow0 = (64 * (wn & 1)) * 128; // wave's B row base (bytes)

  short8 af[4][2]; // A frags of current mq half [mf'][ks]
  short8 b0[2][2]; // B frags nq=0 [nf'][ks]
  short8 b1[2][2]; // B frags nq=1
  f32x4 acc[8][4] = {};

  // ---- prologue: stage K-tiles 0,1; retire kt0; publish
  STAGE_KT(0, 0);
  STAGE_KT(1, 1);
  asm volatile("s_waitcnt vmcnt(8)" ::: "memory");
  __builtin_amdgcn_s_barrier();

#pragma unroll 1
  for (int kt = 0; kt < 16; ++kt) {
    const int cur = kt & 1;
    const char* Ar = &lds[cur][wm][0];
    const char* Br = &lds[cur][2 + (wn >> 1)][0];

    // ---- ph0: read A[mq0] (8) + B[nq0] (4); MFMA quad(0,0)
#pragma unroll
    for (int mf = 0; mf < 4; ++mf)
#pragma unroll
      for (int ks = 0; ks < 2; ++ks)
        af[mf][ks] =
            *(const short8*)(Ar + (16 * mf + lc) * 128 + 64 * ks + alg);
#pragma unroll
    for (int nf = 0; nf < 2; ++nf)
#pragma unroll
      for (int ks = 0; ks < 2; ++ks)
        b0[nf][ks] = *(const short8*)(Br + brow0 + (16 * nf + lc) * 128 +
                                      64 * ks + alg);
    __builtin_amdgcn_s_barrier();
    __builtin_amdgcn_s_setprio(1);
#pragma unroll
    for (int mf = 0; mf < 4; ++mf)
#pragma unroll
      for (int nf = 0; nf < 2; ++nf) {
        acc[mf][nf] = mfma16(af[mf][0], b0[nf][0], acc[mf][nf]);
        acc[mf][nf] = mfma16(af[mf][1], b0[nf][1], acc[mf][nf]);
      }
    __builtin_amdgcn_s_setprio(0);
    __builtin_amdgcn_s_barrier();

    // ---- ph1: read B[nq1] (4); MFMA quad(0,1)
#pragma unroll
    for (int nf = 0; nf < 2; ++nf)
#pragma unroll
      for (int ks = 0; ks < 2; ++ks)
        b1[nf][ks] = *(const short8*)(Br + brow0 + (32 + 16 * nf + lc) * 128 +
                                      64 * ks + alg);
    __builtin_amdgcn_s_barrier();
    __builtin_amdgcn_s_setprio(1);
#pragma unroll
    for (int mf = 0; mf < 4; ++mf)
#pragma unroll
      for (int nf = 0; nf < 2; ++nf) {
        acc[mf][2 + nf] = mfma16(af[mf][0], b1[nf][0], acc[mf][2 + nf]);
        acc[mf][2 + nf] = mfma16(af[mf][1], b1[nf][1], acc[mf][2 + nf]);
      }
    __builtin_amdgcn_s_setprio(0);
    __builtin_amdgcn_s_barrier();

    // ---- ph2: read A[mq1] (8, overwrite af); MFMA quad(1,1)
#pragma unroll
    for (int mf = 0; mf < 4; ++mf)
#pragma unroll
      for (int ks = 0; ks < 2; ++ks)
        af[mf][ks] =
            *(const short8*)(Ar + (64 + 16 * mf + lc) * 128 + 64 * ks + alg);
    __builtin_amdgcn_s_barrier();
    __builtin_amdgcn_s_setprio(1);
#pragma unroll
    for (int mf = 0; mf < 4; ++mf)
#pragma unroll
      for (int nf = 0; nf < 2; ++nf) {
        acc[4 + mf][2 + nf] = mfma16(af[mf][0], b1[nf][0], acc[4 + mf][2 + nf]);
        acc[4 + mf][2 + nf] = mfma16(af[mf][1], b1[nf][1], acc[4 + mf][2 + nf]);
      }
    __builtin_amdgcn_s_setprio(0);
    __builtin_amdgcn_s_barrier();

    // ---- ph3: stage kt+2 -> buf[cur] (reads of buf[cur] all done);
    //           counted-vmcnt gate for kt+1; MFMA quad(1,0) from regs
    if (kt < 14) {
      STAGE_KT(cur, kt + 2);
      asm volatile("s_waitcnt vmcnt(8)" ::: "memory");
    } else {
      asm volatile("s_waitcnt vmcnt(0)" ::: "memory");
    }
    __builtin_amdgcn_s_barrier();
    __builtin_amdgcn_s_setprio(1);
#pragma unroll
    for (int mf = 0; mf < 4; ++mf)
#pragma unroll
      for (int nf = 0; nf < 2; ++nf) {
        acc[4 + mf][nf] = mfma16(af[mf][0], b0[nf][0], acc[4 + mf][nf]);
        acc[4 + mf][nf] = mfma16(af[mf][1], b0[nf][1], acc[4 + mf][nf]);
      }
    __builtin_amdgcn_s_setprio(0);
    __builtin_amdgcn_s_barrier();
  }
#undef STAGE_KT
#undef ST1

  // ---- fused QKV epilogue (bias + scatter; V transposed)
#pragma unroll
  for (int mf = 0; mf < 8; ++mf) {
#pragma unroll
    for (int nf = 0; nf < 4; ++nf) {
#pragma unroll
      for (int r = 0; r < 4; ++r) {
        int m = bm0 + 128 * wm + 16 * mf + 4 * lg4 + r;
        int n = bn0 + 64 * wn + 16 * nf + lc;
        float v = acc[mf][nf][r];
        int proj = n >> 10, win = n & 1023, h = win >> 6, d = win & 63;
        const float* bp = (proj == 0) ? bq : ((proj == 1) ? bk : bv);
        __hip_bfloat16 hv = __float2bfloat16(v + bp[win]);
        int b = m >> 11, lq = m & 2047;
        if (proj == 0)
          Qb[((size_t)(b * 16 + h) * 2048 + lq) * 64 + d] = hv;
        else if (proj == 1)
          Kb[((size_t)(b * 16 + h) * 2048 + lq) * 64 + d] = hv;
        else
          VTb[((size_t)(b * 16 + h) * 64 + d) * 2048 + lq] = hv;
      }
    }
  }
}

// ---------------------------------------------------------------- GEMM (m97)
// kept for the output projection: C = A @ Bt^T + bias -> fp32
template <int EPI, int KDIM>
__global__ __launch_bounds__(256) void gemm128(
    const __hip_bfloat16* __restrict__ A, const __hip_bfloat16* __restrict__ Bt,
    float* __restrict__ Cout, const float* __restrict__ bias,
    const float* __restrict__ bq, const float* __restrict__ bk,
    const float* __restrict__ bv, __hip_bfloat16* __restrict__ Qb,
    __hip_bfloat16* __restrict__ Kb, __hip_bfloat16* __restrict__ VTb) {
  __shared__ __hip_bfloat16 As[128 * 32];
  __shared__ __hip_bfloat16 Bs[128 * 32];
  const int tid = threadIdx.x;
  const int w = tid >> 6, l = tid & 63;
  const int lc = l & 15, lg = l >> 4;
  const int wr = w >> 1, wc = w & 1;
  const int bm0 = blockIdx.x * 128;
  const int bn0 = blockIdx.y * 128;
  const int lrow = l >> 2;
  const int lk = (l & 3) * 8;

  f32x4 acc[4][4] = {};

#pragma unroll 1
  for (int kt = 0; kt < KDIM; kt += 32) {
    if (w < 2) {
#pragma unroll
      for (int i = 0; i < 4; ++i) {
        int rloc = w * 64 + i * 16;
        const __hip_bfloat16* src =
            A + (size_t)(bm0 + rloc + lrow) * KDIM + kt + lk;
        gload_lds16(src, &As[rloc * 32]);
      }
    } else {
#pragma unroll
      for (int i = 0; i < 4; ++i) {
        int rloc = (w - 2) * 64 + i * 16;
        const __hip_bfloat16* src =
            Bt + (size_t)(bn0 + rloc + lrow) * KDIM + kt + lk;
        gload_lds16(src, &Bs[rloc * 32]);
      }
    }
    __syncthreads();
    short8 af[4], bf[4];
#pragma unroll
    for (int mt = 0; mt < 4; ++mt)
      af[mt] = *(const short8*)&As[(wr * 64 + mt * 16 + lc) * 32 + 8 * lg];
#pragma unroll
    for (int nt = 0; nt < 4; ++nt)
      bf[nt] = *(const short8*)&Bs[(wc * 64 + nt * 16 + lc) * 32 + 8 * lg];
#pragma unroll
    for (int mt = 0; mt < 4; ++mt)
#pragma unroll
      for (int nt = 0; nt < 4; ++nt)
        acc[mt][nt] = __builtin_amdgcn_mfma_f32_16x16x32_bf16(
            af[mt], bf[nt], acc[mt][nt], 0, 0, 0);
    __syncthreads();
  }

#pragma unroll
  for (int mt = 0; mt < 4; ++mt) {
#pragma unroll
    for (int nt = 0; nt < 4; ++nt) {
#pragma unroll
      for (int r = 0; r < 4; ++r) {
        int m = bm0 + wr * 64 + mt * 16 + 4 * lg + r;
        int n = bn0 + wc * 64 + nt * 16 + lc;
        float v = acc[mt][nt][r];
        if (EPI == 0) {
          Cout[(size_t)m * 1024 + n] = v + bias[n];
        } else {
          int proj = n >> 10, win = n & 1023, h = win >> 6, d = win & 63;
          const float* bp = (proj == 0) ? bq : ((proj == 1) ? bk : bv);
          __hip_bfloat16 hv = __float2bfloat16(v + bp[win]);
          int b = m >> 11, lq = m & 2047;
          if (proj == 0)
            Qb[((size_t)(b * 16 + h) * 2048 + lq) * 64 + d] = hv;
          else if (proj == 1)
            Kb[((size_t)(b * 16 + h) * 2048 + lq) * 64 + d] = hv;
          else
            VTb[((size_t)(b * 16 + h) * 64 + d) * 2048 + lq] = hv;
        }
      }
    }
  }
}

// ---------------------------------------------------------------- attention
// (unchanged from R5 — measured 133.8 us)
__global__ __launch_bounds__(256, 4) void attn32(
    const __hip_bfloat16* __restrict__ Qb, const __hip_bfloat16* __restrict__ Kb,
    const __hip_bfloat16* __restrict__ VTb, __hip_bfloat16* __restrict__ AO) {
  __shared__ __align__(16) char lds[2][2][8192]; // [buf][K=0/V=1][64 rows x 128B]
  const int tid = threadIdx.x;
  const int w = tid >> 6, l = tid & 63;
  const int q32 = l & 31;
  const int hi = l >> 5;
  const int bh = blockIdx.y;
  const int qb = blockIdx.x;
  const int b = bh >> 4, h = bh & 15;

  const __hip_bfloat16* Qp = Qb + (size_t)bh * SEQ * 64;
  const char* Kg = (const char*)(Kb + (size_t)bh * SEQ * 64);
  const char* Vg = (const char*)(VTb + (size_t)bh * 64 * SEQ);

  const int q0w = qb * 128 + w * 32;
  short8 qf[4];
#pragma unroll
  for (int ds = 0; ds < 4; ++ds)
    qf[ds] = *(const short8*)(Qp + (size_t)(q0w + q32) * 64 + ds * 16 + 8 * hi);

  const int srow = l >> 3;
  const int scol = (16 * (l & 7)) ^ (srow << 4);
  const int i0 = 2 * w, i1 = 2 * w + 1;

#define STAGE_KV(buf, kv0)                                                   \
  {                                                                          \
    gload_lds16(Kg + (size_t)((kv0) + i0 * 8 + srow) * 128 + scol,           \
                &lds[buf][0][i0 * 1024]);                                    \
    gload_lds16(Kg + (size_t)((kv0) + i1 * 8 + srow) * 128 + scol,           \
                &lds[buf][0][i1 * 1024]);                                    \
    gload_lds16(Vg + (size_t)(i0 * 8 + srow) * (SEQ * 2) +                   \
                    (size_t)(kv0) * 2 + scol,                                \
                &lds[buf][1][i0 * 1024]);                                    \
    gload_lds16(Vg + (size_t)(i1 * 8 + srow) * (SEQ * 2) +                   \
                    (size_t)(kv0) * 2 + scol,                                \
                &lds[buf][1][i1 * 1024]);                                    \
  }

  STAGE_KV(0, 0);

  f32x16 o0 = {}, o1 = {};
  float mrun = -INFINITY, lrun = 0.0f;
  const float cs = 0.125f * 1.44269504088896f;
  const int swz = (q32 & 7) << 4;

#pragma unroll 1
  for (int it = 0; it < 32; ++it) {
    const int kv0 = it * 64;
    const int cur = it & 1;
    __syncthreads();
    if (it < 31) STAGE_KV(cur ^ 1, kv0 + 64);

    const char* Kt = lds[cur][0];
    f32x16 s0 = {}, s1 = {};
#pragma unroll
    for (int ds = 0; ds < 4; ++ds) {
      const int c = (32 * ds + 16 * hi) ^ swz;
      short8 k0 = *(const short8*)(Kt + q32 * 128 + c);
      short8 k1 = *(const short8*)(Kt + (32 + q32) * 128 + c);
      s0 = __builtin_amdgcn_mfma_f32_32x32x16_bf16(k0, qf[ds], s0, 0, 0, 0);
      s1 = __builtin_amdgcn_mfma_f32_32x32x16_bf16(k1, qf[ds], s1, 0, 0, 0);
    }

#define M3F(a, b, c) fmaxf(fmaxf((a), (b)), (c))
    float u0 = M3F(s0[0], s0[1], s0[2]);
    float u1 = M3F(s0[3], s0[4], s0[5]);
    float u2 = M3F(s0[6], s0[7], s0[8]);
    float u3 = M3F(s0[9], s0[10], s0[11]);
    float u4 = M3F(s0[12], s0[13], s0[14]);
    float u5 = M3F(s0[15], s1[0], s1[1]);
    float u6 = M3F(s1[2], s1[3], s1[4]);
    float u7 = M3F(s1[5], s1[6], s1[7]);
    float u8 = M3F(s1[8], s1[9], s1[10]);
    float u9 = M3F(s1[11], s1[12], s1[13]);
    float ua = fmaxf(s1[14], s1[15]);
    float t =
        M3F(M3F(u0, u1, u2), M3F(u3, u4, u5), M3F(M3F(u6, u7, u8), u9, ua));
#undef M3F
    t = fmaxf(t, __shfl_xor(t, 32));
    const float tl = t * cs;

    const bool nores = (__all(tl <= mrun + 8.0f) != 0);
    const float mn = nores ? mrun : fmaxf(mrun, tl);

    float p0[16], p1[16];
    float rs = 0.0f;
#pragma unroll
    for (int i = 0; i < 16; ++i) {
      p0[i] = exp2f(fmaf(s0[i], cs, -mn));
      p1[i] = exp2f(fmaf(s1[i], cs, -mn));
      rs += p0[i] + p1[i];
    }
    rs += __shfl_xor(rs, 32);

    if (!nores) {
      const float corr = exp2f(mrun - mn);
      mrun = mn;
      lrun *= corr;
      o0 *= corr;
      o1 *= corr;
    }
    lrun += rs;

    uint32_t pw[4][4];
#pragma unroll
    for (int ks = 0; ks < 4; ++ks) {
      const int base = 8 * (ks & 1);
#pragma unroll
      for (int g = 0; g < 4; ++g) {
        float lo = (ks < 2) ? p0[base + 2 * g] : p1[base + 2 * g];
        float hp = (ks < 2) ? p0[base + 2 * g + 1] : p1[base + 2 * g + 1];
        pw[ks][g] = cvt_pk_bf16(lo, hp);
      }
    }

    const char* Vt = lds[cur][1];
#pragma unroll
    for (int ks = 0; ks < 4; ++ks) {
      union { short8 v; uint32_t u[4]; } pb;
      pb.u[0] = pw[ks][0];
      pb.u[1] = pw[ks][1];
      pb.u[2] = pw[ks][2];
      pb.u[3] = pw[ks][3];
      const int cA = (32 * ks + 8 * hi) ^ swz;
      const int cB = (32 * ks + 16 + 8 * hi) ^ swz;
      union { short8 v; uint64_t u[2]; } a0, a1;
      a0.u[0] = *(const uint64_t*)(Vt + q32 * 128 + cA);
      a0.u[1] = *(const uint64_t*)(Vt + q32 * 128 + cB);
      a1.u[0] = *(const uint64_t*)(Vt + (32 + q32) * 128 + cA);
      a1.u[1] = *(const uint64_t*)(Vt + (32 + q32) * 128 + cB);
      o0 = __builtin_amdgcn_mfma_f32_32x32x16_bf16(a0.v, pb.v, o0, 0, 0, 0);
      o1 = __builtin_amdgcn_mfma_f32_32x32x16_bf16(a1.v, pb.v, o1, 0, 0, 0);
    }
  }

  const float rinv = 1.0f / lrun;
  const size_t orow = (size_t)(b * SEQ + q0w + q32) * 1024 + h * 64;
#pragma unroll
  for (int g = 0; g < 4; ++g) {
    uint2 wa, wb;
    wa.x = cvt_pk_bf16(o0[4 * g + 0] * rinv, o0[4 * g + 1] * rinv);
    wa.y = cvt_pk_bf16(o0[4 * g + 2] * rinv, o0[4 * g + 3] * rinv);
    wb.x = cvt_pk_bf16(o1[4 * g + 0] * rinv, o1[4 * g + 1] * rinv);
    wb.y = cvt_pk_bf16(o1[4 * g + 2] * rinv, o1[4 * g + 3] * rinv);
    *(uint2*)(AO + orow + 8 * g + 4 * hi) = wa;
    *(uint2*)(AO + orow + 32 + 8 * g + 4 * hi) = wb;
  }
#undef STAGE_KV
}

// ---------------------------------------------------------------- launch
extern "C" void kernel_launch(void* const* d_in, const int* in_sizes, int n_in,
                              void* d_out, int out_size, void* d_ws,
                              size_t ws_size, hipStream_t stream) {
  const float* x = (const float*)d_in[0];
  const float* wq = (const float*)d_in[1];
  const float* bq = (const float*)d_in[2];
  const float* wk = (const float*)d_in[3];
  const float* bk = (const float*)d_in[4];
  const float* wv = (const float*)d_in[5];
  const float* bv = (const float*)d_in[6];
  const float* wo = (const float*)d_in[7];
  const float* bo = (const float*)d_in[8];
  float* out = (float*)d_out;
  char* ws = (char*)d_ws;

  // workspace layout (72 MB total)
  __hip_bfloat16* XB = (__hip_bfloat16*)(ws);                  // 16 MB x bf16
  __hip_bfloat16* WT = (__hip_bfloat16*)(ws + (16ull << 20));  // 6 MB WqkvT
  __hip_bfloat16* WOT = (__hip_bfloat16*)(ws + (22ull << 20)); // 2 MB WoT
  __hip_bfloat16* QB = (__hip_bfloat16*)(ws + (24ull << 20));  // 16 MB
  __hip_bfloat16* KB = (__hip_bfloat16*)(ws + (40ull << 20));  // 16 MB
  __hip_bfloat16* VTB = (__hip_bfloat16*)(ws + (56ull << 20)); // 16 MB
  __hip_bfloat16* AO = XB; // reuse: x(bf16) dead after GEMM1

  convert_f32_bf16<<<2048, 256, 0, stream>>>(x, XB, TOK * HIDDEN / 4);
  transpose_to_bf16<<<dim3(16, 16), 256, 0, stream>>>(wq, WT);
  transpose_to_bf16<<<dim3(16, 16), 256, 0, stream>>>(wk, WT + 1024 * 1024);
  transpose_to_bf16<<<dim3(16, 16), 256, 0, stream>>>(wv, WT + 2 * 1024 * 1024);
  transpose_to_bf16<<<dim3(16, 16), 256, 0, stream>>>(wo, WOT);

  // QKV: C[8192,3072] via 256^2 8-phase kernel (fused bias + scatter)
  gemm256_qkv<<<384, 512, 0, stream>>>(XB, WT, bq, bk, bv, QB, KB, VTB);

  attn32<<<dim3(16, 64), 256, 0, stream>>>(QB, KB, VTB, AO);

  // out = AO @ WoT + bo  (fp32 out)
  gemm128<0, 1024><<<dim3(64, 8), 256, 0, stream>>>(
      AO, WOT, out, bo, nullptr, nullptr, nullptr, nullptr, nullptr, nullptr);
}